// Round 10
// baseline (103.888 us; speedup 1.0000x reference)
//
#include <hip/hip_runtime.h>
#include <hip/hip_bf16.h>

typedef __attribute__((ext_vector_type(8))) short short8;
typedef __attribute__((ext_vector_type(16))) float floatx16;

#define HW_TOK 4096
#define KLEN 308
#define DH 64
#define INNER 512

#define KROWS 320                      // K LDS rows incl. zeroed pad rows 308..319
#define VSTRU 328                      // V^T row stride in ushorts (16B multiple)
#define VBASE (KROWS * 64)             // 20480 ushorts
#define KV_TOTAL (VBASE + DH * VSTRU)  // 41472 u = 82944 B
#define NW 8

// round-to-nearest-even f32 -> bf16
__device__ __forceinline__ unsigned short f2bf(float f) {
    union { float f; unsigned u; } x; x.f = f;
    unsigned u = x.u;
    return (unsigned short)((u + 0x7FFFu + ((u >> 16) & 1u)) >> 16);
}
__device__ __forceinline__ unsigned pk2bf(float a, float b) {
    return ((unsigned)f2bf(b) << 16) | (unsigned)f2bf(a);
}

__global__ __launch_bounds__(512, 1)   // 1 block/CU -> 2 waves/SIMD -> 256 VGPR cap
void dd_attn_kernel(const float* __restrict__ q,
                    const float* __restrict__ k,
                    const float* __restrict__ v,
                    const float* __restrict__ dd,
                    float* __restrict__ out) {
    __shared__ unsigned short KV[KV_TOTAL];
    __shared__ unsigned short Pb[NW][2][32][32];   // 32768 B, per-wave dbuf P^T bounce

    const int tid  = threadIdx.x;
    const int lane = tid & 63;
    const int wave = tid >> 6;     // 0..7
    const int half = lane >> 5;    // 0..1  k-half for 32x32x16 frags
    const int l31  = lane & 31;
    const int quad = lane >> 4;
    const int l15  = lane & 15;
    const int prot = 8 * ((l31 >> 1) & 7);   // Pb bank rotation (8u units, keeps 16B align)

    const int bid = blockIdx.x;    // 256 blocks
    const int bh  = bid >> 4;      // 0..15
    const int grp = bid & 15;      // 16 groups x 8 waves x 32 rows = 4096
    const int b = bh >> 3, h = bh & 7;

    const float* qp = q + (size_t)b * HW_TOK * INNER + h * DH;
    const float* kp = k + (size_t)b * KLEN * INNER + h * DH;
    const float* vp = v + (size_t)b * KLEN * INNER + h * DH;
    float* op = out + (size_t)b * HW_TOK * INNER + h * DH;

    // ---- stage K bf16, swizzled 16B chunks ----
    for (int e = tid; e < KLEN * 32; e += 512) {
        int row = e >> 5, d2 = e & 31;
        float2 f = *(const float2*)(kp + (size_t)row * INNER + 2 * d2);
        int c = d2 >> 2;
        int off = row * 64 + (((c ^ (row & 7)) << 3) | ((d2 & 3) << 1));
        *(unsigned*)&KV[off] = pk2bf(f.x, f.y);
    }
    for (int e = tid; e < 12 * 64; e += 512) KV[KLEN * 64 + e] = 0;   // zero K pad rows

    // ---- stage V^T bf16: lane=dh, coalesced row reads, one b128 write per 8 cols ----
    #pragma unroll
    for (int i = 0; i < 5; ++i) {
        int cq = wave + NW * i;                   // 8 waves x 5 = 40 col-chunks
        float f[8];
        #pragma unroll
        for (int j = 0; j < 8; ++j) {
            int col = cq * 8 + j;
            f[j] = (col < KLEN) ? vp[(size_t)col * INNER + lane] : 0.f;
        }
        union { short8 s; unsigned u[4]; } vv;
        #pragma unroll
        for (int j = 0; j < 4; ++j) vv.u[j] = pk2bf(f[2 * j], f[2 * j + 1]);
        int swz = (cq & ~7) | ((cq ^ (lane & 7)) & 7);
        *(short8*)&KV[VBASE + lane * VSTRU + (swz << 3)] = vv.s;
    }
    // ---- region sums: quad r sums dd region r, shfl-broadcast ----
    float rsum = 0.f;
    {
        const float* dp = dd + quad * 1024 + l15 * 4;
        #pragma unroll
        for (int j = 0; j < 16; ++j) {
            float4 f = *(const float4*)(dp + j * 64);
            rsum += f.x + f.y + f.z + f.w;
        }
        #pragma unroll
        for (int off = 1; off < 16; off <<= 1) rsum += __shfl_xor(rsum, off);
    }
    float rsc[4];
    #pragma unroll
    for (int r = 0; r < 4; ++r)
        rsc[r] = 4096.0f / (4.0f * __shfl(rsum, r * 16 + l15));

    __syncthreads();   // the only barrier

    const int q0 = (grp * NW + wave) * 32;
    const int qrow = q0 + l31;

    // ---- Q B-fragments (n=l31, k=half*8+j per 16-k step) ----
    short8 qb[4];
    const float* qr = qp + (size_t)qrow * INNER;
    #pragma unroll
    for (int ks = 0; ks < 4; ++ks) {
        const float* p0 = qr + ks * 16 + half * 8;
        float4 a = *(const float4*)p0;
        float4 c = *(const float4*)(p0 + 4);
        union { short8 s; unsigned u[4]; } u;
        u.u[0] = pk2bf(a.x, a.y); u.u[1] = pk2bf(a.z, a.w);
        u.u[2] = pk2bf(c.x, c.y); u.u[3] = pk2bf(c.z, c.w);
        qb[ks] = u.s;
    }

    // ---- per-lane mask coefficients, log2e folded (exp2 path); -1 = masked ----
    const int mi = (qrow >> 7) * 32 + ((qrow & 63) >> 1);   // nearest-exact 64->32
    float coef[4];
    #pragma unroll
    for (int r = 0; r < 4; ++r)
        coef[r] = (dd[r * 1024 + mi] > 0.5f) ? 0.125f * 1.44269504089f * rsc[r] : -1.0f;

    // ---- no-max unnormalized softmax: logits bounded (|s|<~12), exp2 exact-safe ----
    float l_run = 0.f;
    floatx16 oA[2], oB[2];
    #pragma unroll
    for (int j = 0; j < 16; ++j) { oA[0][j]=0.f; oA[1][j]=0.f; oB[0][j]=0.f; oB[1][j]=0.f; }

    #pragma unroll
    for (int t = 0; t < 10; ++t) {
        // S^T tile: A = K (m=kcol), B = Q (n=qrow)
        const int row = t * 32 + l31;
        floatx16 c;
        #pragma unroll
        for (int j = 0; j < 16; ++j) c[j] = 0.f;
        #pragma unroll
        for (int ks = 0; ks < 4; ++ks) {
            int cc = ks * 2 + half;
            short8 ka = *(const short8*)&KV[row * 64 + ((cc ^ (row & 7)) << 3)];
            c = __builtin_amdgcn_mfma_f32_32x32x16_bf16(ka, qb[ks], c, 0, 0, 0);
        }
        // mask + scale + exp2, accumulate l (no cross-lane ops)
        #pragma unroll
        for (int reg = 0; reg < 16; ++reg) {
            const int C0 = t * 32 + (reg & 3) + 8 * (reg >> 2);   // half=0 kcol
            const int C1 = C0 + 4;                                 // half=1 kcol
            float cfA = (C0 < 77) ? coef[0] : (C0 < 154) ? coef[1]
                      : (C0 < 231) ? coef[2] : (C0 < 308) ? coef[3] : -1.0f;
            float cfB = (C1 < 77) ? coef[0] : (C1 < 154) ? coef[1]
                      : (C1 < 231) ? coef[2] : (C1 < 308) ? coef[3] : -1.0f;
            float cf = half ? cfB : cfA;
            float p = __builtin_amdgcn_exp2f(c[reg] * cf);
            p = (cf > 0.f) ? p : 0.f;
            c[reg] = p;
            l_run += p;
        }
        // P^T bounce (per-wave, t-parity dbuf, bank-rotated)
        const int tb = t & 1;
        unsigned short* pr = &Pb[wave][tb][l31][0];
        #pragma unroll
        for (int g = 0; g < 4; ++g) {
            unsigned u0 = pk2bf(c[4 * g],     c[4 * g + 1]);
            unsigned u1 = pk2bf(c[4 * g + 2], c[4 * g + 3]);
            *(uint2*)&pr[(8 * g + 4 * half + prot) & 31] = make_uint2(u0, u1);
        }
        #pragma unroll
        for (int ks2 = 0; ks2 < 2; ++ks2) {
            short8 pb = *(const short8*)&pr[(16 * ks2 + 8 * half + prot) & 31];
            int cc2 = (t * 2 + ks2) * 2 + half;
            #pragma unroll
            for (int mt = 0; mt < 2; ++mt) {
                int vrow = 32 * mt + l31;
                int swz = (cc2 & ~7) | ((cc2 ^ (vrow & 7)) & 7);
                short8 va = *(const short8*)&KV[VBASE + vrow * VSTRU + (swz << 3)];
                if (ks2 == 0)
                    oA[mt] = __builtin_amdgcn_mfma_f32_32x32x16_bf16(va, pb, oA[mt], 0, 0, 0);
                else
                    oB[mt] = __builtin_amdgcn_mfma_f32_32x32x16_bf16(va, pb, oB[mt], 0, 0, 0);
            }
        }
    }

    // ---- single cross-lane reduction, normalize, store out^T ----
    l_run += __shfl_xor(l_run, 32);
    const float inv = 1.0f / l_run;
    float* o = op + (size_t)qrow * INNER;
    #pragma unroll
    for (int mt = 0; mt < 2; ++mt) {
        #pragma unroll
        for (int g = 0; g < 4; ++g) {
            float4 ov;
            ov.x = (oA[mt][4 * g]     + oB[mt][4 * g])     * inv;
            ov.y = (oA[mt][4 * g + 1] + oB[mt][4 * g + 1]) * inv;
            ov.z = (oA[mt][4 * g + 2] + oB[mt][4 * g + 2]) * inv;
            ov.w = (oA[mt][4 * g + 3] + oB[mt][4 * g + 3]) * inv;
            *(float4*)&o[32 * mt + 8 * g + 4 * half] = ov;
        }
    }
}

extern "C" void kernel_launch(void* const* d_in, const int* in_sizes, int n_in,
                              void* d_out, int out_size, void* d_ws, size_t ws_size,
                              hipStream_t stream) {
    const float* q  = (const float*)d_in[0];
    const float* k  = (const float*)d_in[1];
    const float* v  = (const float*)d_in[2];
    const float* dd = (const float*)d_in[3];
    float* out = (float*)d_out;
    dd_attn_kernel<<<dim3(256), dim3(512), 0, stream>>>(q, k, v, dd, out);
}

// Round 11
// 91.064 us; speedup vs baseline: 1.1408x; 1.1408x over previous
//
#include <hip/hip_runtime.h>
#include <hip/hip_bf16.h>

typedef __attribute__((ext_vector_type(8))) short short8;
typedef __attribute__((ext_vector_type(16))) float floatx16;

#define HW_TOK 4096
#define KLEN 308
#define DH 64
#define INNER 512

#define VSTRU 328                      // V^T row stride in ushorts
#define VBASE (KLEN * 64)              // 19712 u (K region: exactly 308 rows, no pad)
#define KV_TOTAL (VBASE + DH * VSTRU)  // 40704 u = 81408 B  -> 2 blocks/CU
#define NW 8

// round-to-nearest-even f32 -> bf16
__device__ __forceinline__ unsigned short f2bf(float f) {
    union { float f; unsigned u; } x; x.f = f;
    unsigned u = x.u;
    return (unsigned short)((u + 0x7FFFu + ((u >> 16) & 1u)) >> 16);
}
__device__ __forceinline__ unsigned pk2bf(float a, float b) {
    return ((unsigned)f2bf(b) << 16) | (unsigned)f2bf(a);
}

// (512,2) = min 2 blocks/CU on this toolchain (R4-measured) -> VGPR cap 128.
// LDS 81408 B lets 2 blocks fit -> 16 waves/CU.
__global__ __launch_bounds__(512, 2)
void dd_attn_kernel(const float* __restrict__ q,
                    const float* __restrict__ k,
                    const float* __restrict__ v,
                    const float* __restrict__ dd,
                    float* __restrict__ out) {
    __shared__ unsigned short KV[KV_TOTAL];

    const int tid  = threadIdx.x;
    const int lane = tid & 63;
    const int wave = tid >> 6;     // 0..7
    const int half = lane >> 5;    // k-half for 32x32x16 frags
    const int l31  = lane & 31;
    const int quad = lane >> 4;
    const int l15  = lane & 15;

    const int bid = blockIdx.x;    // 256 blocks
    const int bh  = bid >> 4;      // 0..15
    const int grp = bid & 15;      // 16 groups x 8 waves x 32 rows = 4096
    const int b = bh >> 3, h = bh & 7;

    const float* qp = q + (size_t)b * HW_TOK * INNER + h * DH;
    const float* kp = k + (size_t)b * KLEN * INNER + h * DH;
    const float* vp = v + (size_t)b * KLEN * INNER + h * DH;
    float* op = out + (size_t)b * HW_TOK * INNER + h * DH;

    // ---- stage K bf16, swizzled 16B chunks (rows 308..319 of tile 9 read V region:
    //      garbage, provably masked by compile-time kcol>=308 selects) ----
    for (int e = tid; e < KLEN * 32; e += 512) {
        int row = e >> 5, d2 = e & 31;
        float2 f = *(const float2*)(kp + (size_t)row * INNER + 2 * d2);
        int c = d2 >> 2;
        int off = row * 64 + (((c ^ (row & 7)) << 3) | ((d2 & 3) << 1));
        *(unsigned*)&KV[off] = pk2bf(f.x, f.y);
    }
    // ---- stage V^T bf16: lane=dh, coalesced row reads, one b128 write per 8 cols;
    //      cols 308..319 zeroed (P=0 there, but V must be finite to avoid 0*Inf=NaN) ----
    #pragma unroll
    for (int i = 0; i < 5; ++i) {
        int cq = wave + NW * i;                   // 8 waves x 5 = 40 col-chunks
        float f[8];
        #pragma unroll
        for (int j = 0; j < 8; ++j) {
            int col = cq * 8 + j;
            f[j] = (col < KLEN) ? vp[(size_t)col * INNER + lane] : 0.f;
        }
        union { short8 s; unsigned u[4]; } vv;
        #pragma unroll
        for (int j = 0; j < 4; ++j) vv.u[j] = pk2bf(f[2 * j], f[2 * j + 1]);
        int swz = (cq & ~7) | ((cq ^ (lane & 7)) & 7);
        *(short8*)&KV[VBASE + lane * VSTRU + (swz << 3)] = vv.s;
    }
    // ---- region sums: quad r sums dd region r, shfl-broadcast ----
    float rsum = 0.f;
    {
        const float* dp = dd + quad * 1024 + l15 * 4;
        #pragma unroll
        for (int j = 0; j < 16; ++j) {
            float4 f = *(const float4*)(dp + j * 64);
            rsum += f.x + f.y + f.z + f.w;
        }
        #pragma unroll
        for (int off = 1; off < 16; off <<= 1) rsum += __shfl_xor(rsum, off);
    }
    float rsc[4];
    #pragma unroll
    for (int r = 0; r < 4; ++r)
        rsc[r] = 4096.0f / (4.0f * __shfl(rsum, r * 16 + l15));

    __syncthreads();   // the only barrier

    const int q0 = (grp * NW + wave) * 32;
    const int qrow = q0 + l31;

    // ---- Q B-fragments (n=l31=qrow, k=half*8+j per 16-k step) ----
    short8 qb[4];
    const float* qr = qp + (size_t)qrow * INNER;
    #pragma unroll
    for (int ks = 0; ks < 4; ++ks) {
        const float* p0 = qr + ks * 16 + half * 8;
        float4 a = *(const float4*)p0;
        float4 c = *(const float4*)(p0 + 4);
        union { short8 s; unsigned u[4]; } u;
        u.u[0] = pk2bf(a.x, a.y); u.u[1] = pk2bf(a.z, a.w);
        u.u[2] = pk2bf(c.x, c.y); u.u[3] = pk2bf(c.z, c.w);
        qb[ks] = u.s;
    }

    // ---- per-lane mask coefficients, log2e folded; -1 = masked ----
    const int mi = (qrow >> 7) * 32 + ((qrow & 63) >> 1);   // nearest-exact 64->32
    float coef[4];
    #pragma unroll
    for (int r = 0; r < 4; ++r)
        coef[r] = (dd[r * 1024 + mi] > 0.5f) ? 0.125f * 1.44269504089f * rsc[r] : -1.0f;

    // ---- no-max unnormalized softmax (logits bounded, exp2-safe) ----
    float l0 = 0.f, l1 = 0.f, l2 = 0.f, l3 = 0.f;
    floatx16 oacc[2];
    #pragma unroll
    for (int j = 0; j < 16; ++j) { oacc[0][j] = 0.f; oacc[1][j] = 0.f; }

    #pragma unroll
    for (int t = 0; t < 10; ++t) {
        // S^T tile: A = K (m=kcol), B = Q (n=qrow); lane col = qrow = l31
        const int row = t * 32 + l31;
        floatx16 c;
        #pragma unroll
        for (int j = 0; j < 16; ++j) c[j] = 0.f;
        #pragma unroll
        for (int ks = 0; ks < 4; ++ks) {
            int cc = ks * 2 + half;
            short8 ka = *(const short8*)&KV[row * 64 + ((cc ^ (row & 7)) << 3)];
            c = __builtin_amdgcn_mfma_f32_32x32x16_bf16(ka, qb[ks], c, 0, 0, 0);
        }
        // mask + scale + exp2 (kcol per reg = t*32 + (reg&3)+8*(reg>>2)+4*half)
        #pragma unroll
        for (int reg = 0; reg < 16; ++reg) {
            const int C0 = t * 32 + (reg & 3) + 8 * (reg >> 2);
            const int C1 = C0 + 4;
            float cfA = (C0 < 77) ? coef[0] : (C0 < 154) ? coef[1]
                      : (C0 < 231) ? coef[2] : (C0 < 308) ? coef[3] : -1.0f;
            float cfB = (C1 < 77) ? coef[0] : (C1 < 154) ? coef[1]
                      : (C1 < 231) ? coef[2] : (C1 < 308) ? coef[3] : -1.0f;
            float cf = half ? cfB : cfA;
            float p = __builtin_amdgcn_exp2f(c[reg] * cf);
            p = (cf > 0.f) ? p : 0.f;
            c[reg] = p;
            if ((reg & 3) == 0) l0 += p; else if ((reg & 3) == 1) l1 += p;
            else if ((reg & 3) == 2) l2 += p; else l3 += p;
        }
        // ---- P -> A-operand via register exchange (no LDS round-trip) ----
        // pack: d[g] = kcols {o(2g), o(2g+1)} where o(r)=(r&3)+8*(r>>2)+4*half
        unsigned d[8], pd[8];
        #pragma unroll
        for (int g = 0; g < 8; ++g) d[g] = pk2bf(c[2 * g], c[2 * g + 1]);
        #pragma unroll
        for (int g = 0; g < 8; ++g) pd[g] = (unsigned)__shfl_xor((int)d[g], 32);
        union { short8 s; unsigned u[4]; } f0, f1;
        f0.u[0] = half ? pd[2] : d[0];
        f0.u[1] = half ? pd[3] : d[1];
        f0.u[2] = half ? d[2]  : pd[0];
        f0.u[3] = half ? d[3]  : pd[1];
        f1.u[0] = half ? pd[6] : d[4];
        f1.u[1] = half ? pd[7] : d[5];
        f1.u[2] = half ? d[6]  : pd[4];
        f1.u[3] = half ? d[7]  : pd[5];
        // PV: out += P·V ; B = V^T from LDS (same reads as before)
        #pragma unroll
        for (int ks2 = 0; ks2 < 2; ++ks2) {
            short8 pa = ks2 ? f1.s : f0.s;
            int cc2 = (t * 2 + ks2) * 2 + half;
            #pragma unroll
            for (int mt = 0; mt < 2; ++mt) {
                int vrow = 32 * mt + l31;
                int swz = (cc2 & ~7) | ((cc2 ^ (vrow & 7)) & 7);
                short8 vb = *(const short8*)&KV[VBASE + vrow * VSTRU + (swz << 3)];
                oacc[mt] = __builtin_amdgcn_mfma_f32_32x32x16_bf16(pa, vb, oacc[mt], 0, 0, 0);
            }
        }
    }

    // ---- l per qrow (lane l31), complete across halves, broadcast per reg ----
    float l_run = (l0 + l1) + (l2 + l3);
    l_run += __shfl_xor(l_run, 32);

    // ---- normalize + store: out C-layout lane=dh=32mt+l31, row per reg ----
    #pragma unroll
    for (int reg = 0; reg < 16; ++reg) {
        const int qrl = (reg & 3) + 8 * (reg >> 2) + 4 * half;   // wave-local q row
        float lr = __shfl(l_run, qrl);                            // broadcast (uniform idx)
        float inv = 1.0f / lr;
        float* o = op + (size_t)(q0 + qrl) * INNER + l31;
        o[0]  = oacc[0][reg] * inv;
        o[32] = oacc[1][reg] * inv;
    }
}

extern "C" void kernel_launch(void* const* d_in, const int* in_sizes, int n_in,
                              void* d_out, int out_size, void* d_ws, size_t ws_size,
                              hipStream_t stream) {
    const float* q  = (const float*)d_in[0];
    const float* k  = (const float*)d_in[1];
    const float* v  = (const float*)d_in[2];
    const float* dd = (const float*)d_in[3];
    float* out = (float*)d_out;
    dd_attn_kernel<<<dim3(256), dim3(512), 0, stream>>>(q, k, v, dd, out);
}